// Round 4
// baseline (74.087 us; speedup 1.0000x reference)
//
#include <hip/hip_runtime.h>

// out[b,i] = relu( max_{j=1..64}( hf_pad[b,i+j] - j ) - hf[b,i] )
// With g[k] = hf_pad[k] - k:  out[i] = relu( max_{k=i+1..i+64} g[k] - g[i] )
//
// Register Gil-Werman, 16 consecutive elements per lane (1024/wave).
// Window (i, i+64] at lane L pos t (i = base + 16L + t):
//   own-lane suffix suf[t+1..15]
// + full lanes L+1..L+3 (realmid, via clamped shfl_down doubling)
// + prefix[0..t] of lane L+4   (virtual lanes 64..67 = halo blocks 0..3)
// Halo (64 elems past chunk) lives in lanes 0..3 in NATURAL layout (16/lane)
// with global-halo prefixes built in-register + 3-shuffle carry scan, so the
// combine needs a single rotation bpermute per t with source select.
// DS ops: 3 (agg) + 3 (carry) + 16 (rotate) = 22 per 1024 outputs.

#define N_COLS 4096
#define CHUNK 1024
#define NEG_INF (-3.0e38f)

typedef float vfloat4 __attribute__((ext_vector_type(4)));  // native vec for nontemporal builtin

__global__ __launch_bounds__(256) void slide_max_kernel(
    const float* __restrict__ hf, float* __restrict__ out) {
  const int lane = threadIdx.x & 63;
  const int wid = (blockIdx.x << 2) | (threadIdx.x >> 6);  // global wave id
  const int row = wid >> 2;                                // 4 chunks per row
  const int chunk = wid & 3;
  const int base = chunk * CHUNK;

  const float* rowp = hf + (size_t)row * N_COLS;
  float* outp = out + (size_t)row * N_COLS;

  // ---- load 16 consecutive floats per lane (four dwordx4), compute g ----
  const vfloat4* rp4 = (const vfloat4*)(rowp + base);
  vfloat4 v0 = rp4[4 * lane + 0];
  vfloat4 v1 = rp4[4 * lane + 1];
  vfloat4 v2 = rp4[4 * lane + 2];
  vfloat4 v3 = rp4[4 * lane + 3];
  float x[16] = {v0.x, v0.y, v0.z, v0.w, v1.x, v1.y, v1.z, v1.w,
                 v2.x, v2.y, v2.z, v2.w, v3.x, v3.y, v3.z, v3.w};
  const float kf = (float)(base + 16 * lane);
#pragma unroll
  for (int t = 0; t < 16; ++t) x[t] -= (kf + (float)t);

  // ---- halo: lanes 0..3 own 16 consecutive halo elements each (g-space) ----
  float hl[16];
#pragma unroll
  for (int t = 0; t < 16; ++t) hl[t] = NEG_INF;
  if (lane < 4) {
    const float hbf = (float)(base + CHUNK + 16 * lane);
    if (chunk < 3) {  // halo fully inside the row
      const vfloat4* hq4 = (const vfloat4*)(rowp + base + CHUNK);
      vfloat4 h0 = hq4[4 * lane + 0];
      vfloat4 h1 = hq4[4 * lane + 1];
      vfloat4 h2 = hq4[4 * lane + 2];
      vfloat4 h3 = hq4[4 * lane + 3];
      float hh[16] = {h0.x, h0.y, h0.z, h0.w, h1.x, h1.y, h1.z, h1.w,
                      h2.x, h2.y, h2.z, h2.w, h3.x, h3.y, h3.z, h3.w};
#pragma unroll
      for (int t = 0; t < 16; ++t) hl[t] = hh[t] - (hbf + (float)t);
    } else {  // halo is the reference's -1000 right-pad (in g-space)
#pragma unroll
      for (int t = 0; t < 16; ++t) hl[t] = -1000.0f - (hbf + (float)t);
    }
  }

  // ---- per-lane serial prefix/suffix max scans ----
  float pre[16], suf[16];
  pre[0] = x[0];
#pragma unroll
  for (int t = 1; t < 16; ++t) pre[t] = fmaxf(pre[t - 1], x[t]);
  suf[15] = x[15];
#pragma unroll
  for (int t = 14; t >= 0; --t) suf[t] = fmaxf(suf[t + 1], x[t]);
  const float m = pre[15];  // lane aggregate

  // ---- halo local prefixes + exclusive carry scan among lanes 0..3 ----
  float hpre[16];
  hpre[0] = hl[0];
#pragma unroll
  for (int t = 1; t < 16; ++t) hpre[t] = fmaxf(hpre[t - 1], hl[t]);
  const float agg = hpre[15];
  const float e1 = __shfl_up(agg, 1);
  const float inc1 = (lane >= 1) ? fmaxf(agg, e1) : agg;
  const float e2 = __shfl_up(inc1, 2);
  const float inc2 = (lane >= 2) ? fmaxf(inc1, e2) : inc1;
  float exc = __shfl_up(inc2, 1);  // exclusive prefix of halo-block aggregates
  if (lane == 0) exc = NEG_INF;

  // ---- realmid = max over REAL lanes L+1..min(L+3,63) ----
  const float w2 = fmaxf(m, __shfl_down(m, 1));
  const float a = __shfl_down(w2, 1);  // max(m[L+1..min(L+2,63)])
  const float b = __shfl_down(m, 3);   // m[L+3], valid L<=60
  const float realmid = (lane <= 60) ? fmaxf(a, b)
                      : (lane <= 62) ? a
                                     : NEG_INF;

  // ---- combine: one rotation bpermute per t, source-selected ----
  const int donor = (lane + 4) & 63;   // lanes 60..63 -> halo lanes 0..3
  const bool haloSrc = (lane < 4);
  float o[16];
#pragma unroll
  for (int t = 0; t < 16; ++t) {
    const float sel = haloSrc ? fmaxf(hpre[t], exc) : pre[t];
    const float third = __shfl(sel, donor);
    const float sufs = (t < 15) ? suf[t + 1] : NEG_INF;
    const float mw = fmaxf(fmaxf(sufs, realmid), third);
    o[t] = fmaxf(mw - x[t], 0.0f);
  }

  vfloat4* op4 = (vfloat4*)(outp + base);
  vfloat4 s0 = {o[0], o[1], o[2], o[3]};
  vfloat4 s1 = {o[4], o[5], o[6], o[7]};
  vfloat4 s2 = {o[8], o[9], o[10], o[11]};
  vfloat4 s3 = {o[12], o[13], o[14], o[15]};
  __builtin_nontemporal_store(s0, &op4[4 * lane + 0]);
  __builtin_nontemporal_store(s1, &op4[4 * lane + 1]);
  __builtin_nontemporal_store(s2, &op4[4 * lane + 2]);
  __builtin_nontemporal_store(s3, &op4[4 * lane + 3]);
}

extern "C" void kernel_launch(void* const* d_in, const int* in_sizes, int n_in,
                              void* d_out, int out_size, void* d_ws, size_t ws_size,
                              hipStream_t stream) {
  const float* hf = (const float*)d_in[0];
  float* out = (float*)d_out;
  const int total = in_sizes[0];
  const int rows = total / N_COLS;                 // 1024
  const int waves = rows * (N_COLS / CHUNK);       // 4096 waves
  const int grid = waves / 4;                      // 1024 workgroups
  slide_max_kernel<<<grid, 256, 0, stream>>>(hf, out);
}

// Round 5
// 66.942 us; speedup vs baseline: 1.1067x; 1.1067x over previous
//
#include <hip/hip_runtime.h>

// out[b,i] = relu( max_{j=1..64}( hf_pad[b,i+j] - j ) - hf[b,i] )
// With g[k] = hf_pad[k] - k:  out[i] = relu( max_{k=i+1..i+64} g[k] - g[i] )
//
// Register-transposed Gil-Werman: each lane owns 8 CONSECUTIVE elements
// (chunk of 512 per wave). Window (i, i+64] at lane L pos t decomposes as:
//   own-lane suffix  suf[t+1..7]
// + full lanes L+1..L+7 (aggregate sliding max via clamped doubling)
// + lane L+8 prefix pre[0..t]            (lanes 0..55)
// or, for lanes 56..63 (window crosses chunk end):
// + lanes L+1..63 aggregates (tail) + halo prefix hp[0..8*(L-56)+t]
// 26 wave64 shuffles per 512 outputs. This is the R2 config (best measured:
// 68.13 us) + nontemporal output stores; E=16 variant (R4) measured 74.1 us
// but harness fill drift explains most of it — this run disambiguates.

#define N_COLS 4096
#define CHUNK 512
#define NEG_INF (-3.0e38f)

typedef float vfloat4 __attribute__((ext_vector_type(4)));

__global__ __launch_bounds__(256) void slide_max_kernel(
    const float* __restrict__ hf, float* __restrict__ out) {
  const int lane = threadIdx.x & 63;
  const int wid = (blockIdx.x << 2) | (threadIdx.x >> 6);  // global wave id
  const int row = wid >> 3;                                // 8 chunks per row
  const int chunk = wid & 7;
  const int base = chunk * CHUNK;

  const float* rowp = hf + (size_t)row * N_COLS;
  float* outp = out + (size_t)row * N_COLS;

  // ---- load 8 consecutive floats per lane (two dwordx4), compute g ----
  const vfloat4* rp4 = (const vfloat4*)(rowp + base);
  vfloat4 v0 = rp4[2 * lane];
  vfloat4 v1 = rp4[2 * lane + 1];
  float x[8] = {v0.x, v0.y, v0.z, v0.w, v1.x, v1.y, v1.z, v1.w};
  const float kf = (float)(base + 8 * lane);
#pragma unroll
  for (int t = 0; t < 8; ++t) x[t] -= (kf + (float)t);

  // ---- halo element base+512+lane (1/lane, transposed, coalesced) ----
  const int hk = base + CHUNK + lane;
  const float hh = (hk < N_COLS) ? rowp[hk] : -1000.0f;  // row-end sentinel
  const float gh = hh - (float)hk;

  // ---- per-lane serial prefix/suffix max scans ----
  float pre[8], suf[8];
  pre[0] = x[0];
#pragma unroll
  for (int t = 1; t < 8; ++t) pre[t] = fmaxf(pre[t - 1], x[t]);
  suf[7] = x[7];
#pragma unroll
  for (int t = 6; t >= 0; --t) suf[t] = fmaxf(suf[t + 1], x[t]);
  const float m = pre[7];  // lane aggregate

  // ---- clamped doubling over lane aggregates ----
  const float w2 = fmaxf(m, __shfl_down(m, 1));
  const float w4 = fmaxf(w2, __shfl_down(w2, 2));
  const float a = __shfl_down(w4, 1);  // max(m[L+1..min(L+4,63)]), valid L<=62
  const float b = __shfl_down(w4, 4);  // max(m[L+4..min(L+7,63)]), valid L<=59
  const float midA = fmaxf(a, b);      // lanes <=55: max(m[L+1..L+7])
  const float tail = (lane <= 59) ? fmaxf(a, b)
                   : (lane <= 62) ? a
                                  : NEG_INF;

  // ---- prefixes of lane L+8 ----
  float preN[8];
#pragma unroll
  for (int t = 0; t < 8; ++t) preN[t] = __shfl_down(pre[t], 8);

  // ---- halo prefix scan across lanes (inclusive max-scan) ----
  float hp = gh;
#pragma unroll
  for (int d = 1; d < 64; d <<= 1) hp = fmaxf(hp, __shfl_up(hp, d));

  const bool hiLane = (lane >= 56);
  const int hidx = (lane & 7) << 3;  // halo prefix base index for hi lanes
  const float second = hiLane ? tail : midA;

  // ---- combine + relu ----
  float o[8];
#pragma unroll
  for (int t = 0; t < 8; ++t) {
    const float third_hi = __shfl(hp, hidx + t);  // bpermute; ignored lo lanes
    const float third = hiLane ? third_hi : preN[t];
    const float sufs = (t < 7) ? suf[t + 1] : NEG_INF;
    const float mw = fmaxf(fmaxf(sufs, second), third);
    o[t] = fmaxf(mw - x[t], 0.0f);
  }

  // ---- nontemporal vector stores (streamed output, skip L2 allocate) ----
  vfloat4* op4 = (vfloat4*)(outp + base);
  vfloat4 s0 = {o[0], o[1], o[2], o[3]};
  vfloat4 s1 = {o[4], o[5], o[6], o[7]};
  __builtin_nontemporal_store(s0, &op4[2 * lane]);
  __builtin_nontemporal_store(s1, &op4[2 * lane + 1]);
}

extern "C" void kernel_launch(void* const* d_in, const int* in_sizes, int n_in,
                              void* d_out, int out_size, void* d_ws, size_t ws_size,
                              hipStream_t stream) {
  const float* hf = (const float*)d_in[0];
  float* out = (float*)d_out;
  const int total = in_sizes[0];
  const int rows = total / N_COLS;                   // 1024
  const int waves = rows * (N_COLS / CHUNK);         // 8192 waves
  const int grid = waves / 4;                        // 2048 workgroups
  slide_max_kernel<<<grid, 256, 0, stream>>>(hf, out);
}